// Round 9
// baseline (436.719 us; speedup 1.0000x reference)
//
#include <hip/hip_runtime.h>

typedef unsigned short ushort_t;

#define Bb 32
#define Hh 256
#define Ll 2048
#define Nn 64
#define BHL 16777216

typedef __bf16 bf16x8 __attribute__((ext_vector_type(8)));
typedef float f32x4 __attribute__((ext_vector_type(4)));
typedef unsigned int uint4v __attribute__((ext_vector_type(4)));

__device__ __forceinline__ ushort_t f2bf(float f) {
    unsigned int u = __float_as_uint(f);
    unsigned int r = ((u >> 16) & 1u) + 0x7fffu;
    return (ushort_t)((u + r) >> 16);
}
__device__ __forceinline__ float bf2f(ushort_t h) {
    return __uint_as_float(((unsigned int)h) << 16);
}
__device__ __forceinline__ float gelu_tanh(float v) {
    float u = 0.7978845608028654f * fmaf(0.044715f * v, v * v, v);
    float e = __expf(2.f * u);
    float th = 1.f - 2.f / (e + 1.f);
    return 0.5f * v * (1.f + th);
}
__device__ __forceinline__ float gate_fn(float v) {
    float sg = 1.f / (1.f + __expf(-v));
    float e2 = __expf(2.f * v);
    float th = 1.f - 2.f / (e2 + 1.f);
    return th * sg;
}
__device__ __forceinline__ uint4v rev8v(uint4v a) {
    union { uint4v v; ushort_t s8[8]; } x, y;
    x.v = a;
    #pragma unroll
    for (int j = 0; j < 8; ++j) y.s8[j] = x.s8[7 - j];
    return y.v;
}

// ---------------- prep: tb GEMM + weight fragment repack ----------------
__global__ __launch_bounds__(256) void prep_kernel(
    const float* __restrict__ t, const float* __restrict__ Wt, const float* __restrict__ bt,
    const float* __restrict__ Wout, const float* __restrict__ Wf,
    const float* __restrict__ bout, const float* __restrict__ bfb,
    const float* __restrict__ W1, const float* __restrict__ b1,
    const float* __restrict__ W2, const float* __restrict__ b2,
    float* __restrict__ tb, float* __restrict__ bc, float* __restrict__ b12,
    ushort_t* __restrict__ wcf, ushort_t* __restrict__ w12f)
{
    int bx = blockIdx.x, tid = threadIdx.x;
    __shared__ float trow[256];
    if (bx < 32) {
        trow[tid] = t[bx * 256 + tid];
        __syncthreads();
        float acc = bt[tid];
        #pragma unroll 4
        for (int hh = 0; hh < 256; ++hh) acc = fmaf(trow[hh], Wt[tid * 256 + hh], acc);
        tb[bx * 256 + tid] = acc;
    } else if (bx < 64) {
        int gt = (bx - 32) * 256 + tid;       // 0..8191
        if (gt < 256) bc[gt] = bout[gt] + bfb[gt];
        if (gt < 512) b12[gt] = (gt < 256) ? b1[gt] : b2[gt - 256];
        // Wc_frag: 16 mtiles x 9 kchunks x 64 lanes x 8  (K=288: [Wout | Wf])
        for (int fg = gt; fg < 9216; fg += 8192) {
            int mt = fg / 576, rem = fg % 576;
            int kc = rem >> 6, lane = rem & 63;
            int m = mt * 16 + (lane & 15);
            int kb = kc * 32 + (lane >> 4) * 8;
            #pragma unroll
            for (int j = 0; j < 8; ++j) {
                int k = kb + j;
                float v = (k < 256) ? Wout[m * 256 + k] : Wf[m * 32 + (k - 256)];
                wcf[(size_t)fg * 8 + j] = f2bf(v);
            }
        }
    } else {
        int gt = (bx - 64) * 256 + tid;       // 0..8191
        // W12_frag: 32 mtiles x 8 kchunks x 64 lanes x 8  (M=512: [W1 ; W2])
        for (int fg = gt; fg < 16384; fg += 8192) {
            int mt = fg >> 9, rem = fg & 511;
            int kc = rem >> 6, lane = rem & 63;
            int m = mt * 16 + (lane & 15);
            int kb = kc * 32 + (lane >> 4) * 8;
            #pragma unroll
            for (int j = 0; j < 8; ++j) {
                int k = kb + j;
                float v = (m < 256) ? W1[m * 256 + k] : W2[(m - 256) * 256 + k];
                w12f[(size_t)fg * 8 + j] = f2bf(v);
            }
        }
    }
}

// ---------------- MERGED prep2 + ln (measured neutral vs split; saves a launch) ----------------
// blocks [0,512): prep2 ; blocks [512,1536): ln
__global__ __launch_bounds__(256) void prep2ln_kernel(
    const float* __restrict__ log_dt, const float* __restrict__ logA, const float* __restrict__ Aimg,
    const float* __restrict__ C_re, const float* __restrict__ C_im,
    float* __restrict__ drg, float* __restrict__ dig,
    ushort_t* __restrict__ Mfrag, ushort_t* __restrict__ Vfrag,
    const float* __restrict__ x, const float* __restrict__ tb,
    const float* __restrict__ ln_g, const float* __restrict__ ln_b,
    ushort_t* __restrict__ zbf)
{
    __shared__ __align__(16) char smem[68608];
    int bxg = blockIdx.x, tid = threadIdx.x;
    if (bxg < 512) {
        // ================= prep2 body =================
        float* drL = (float*)smem;             // 64
        float* diL = drL + 64;                 // 64
        float* crL = drL + 128;                // 64
        float* ciL = drL + 192;                // 64
        float* ktab = drL + 256;               // 128
        ushort_t* bndL = (ushort_t*)(smem + 1536);  // 128*128 ushort = 32768 B
        int bx = bxg;
        int h = bx >> 1, dir = bx & 1;
        if (tid < 64) {
            int n = tid;
            int idx = h * 64 + n;
            float dt = __expf(log_dt[h]);
            float Ar = -__expf(logA[idx]);
            float Ai = Aimg[idx];
            float dr = dt * Ar, di = dt * Ai;
            float er = __expf(dr);
            float wr_ = er * __cosf(di), wi_ = er * __sinf(di);
            float nr = wr_ - 1.f, ni = wi_;
            float inv = 1.f / (Ar * Ar + Ai * Ai);
            float qr = (nr * Ar + ni * Ai) * inv;
            float qi = (ni * Ar - nr * Ai) * inv;
            float cr = C_re[dir * 16384 + idx], ci = C_im[dir * 16384 + idx];
            drL[n] = dr; diL[n] = di;
            crL[n] = 2.f * (cr * qr - ci * qi);
            ciL[n] = 2.f * (cr * qi + ci * qr);
            if (dir == 0) { drg[idx] = dr; dig[idx] = di; }
        }
        __syncthreads();
        if (tid < 128) {
            int i = tid;
            float e = (float)(i + 1 - dir);
            #pragma unroll 4
            for (int n = 0; n < 64; ++n) {
                float ex = __expf(e * drL[n]);
                float ph = e * diL[n];
                float pr = ex * __cosf(ph), pi = ex * __sinf(ph);
                bndL[i * 128 + n]      = f2bf(crL[n] * pr - ciL[n] * pi);
                bndL[i * 128 + 64 + n] = f2bf(-(crL[n] * pi + ciL[n] * pr));
            }
        } else {
            int d = tid - 128;
            float e = (float)d;
            float acc = 0.f;
            #pragma unroll 4
            for (int n = 0; n < 64; ++n) {
                float ex = __expf(e * drL[n]);
                float ph = e * diL[n];
                acc += crL[n] * (ex * __cosf(ph)) - ciL[n] * (ex * __sinf(ph));
            }
            ktab[d] = acc;
        }
        __syncthreads();
        size_t base = (size_t)bx << 15;
        for (int idx = tid; idx < 32768; idx += 256) {
            int j = idx & 7, lane = (idx >> 3) & 63, kc = (idx >> 9) & 7, mt = idx >> 12;
            int m = mt * 16 + (lane & 15);
            int k = kc * 32 + (lane >> 4) * 8 + j;
            float v;
            if (k < 128) {
                int d = m - k - dir;
                v = (d >= 0) ? ktab[d] : 0.f;
            } else {
                v = bf2f(bndL[m * 128 + (k - 128)]);
            }
            Mfrag[base + idx] = f2bf(v);
        }
        if (dir == 0) {
            size_t vbase = (size_t)h << 14;
            for (int idx = tid; idx < 16384; idx += 256) {
                int j = idx & 7, lane = (idx >> 3) & 63, kc = (idx >> 9) & 3, mt = idx >> 11;
                int s = mt * 16 + (lane & 15);
                int k = kc * 32 + (lane >> 4) * 8 + j;
                int n = s & 63;
                float e = (float)(127 - k);
                float ex = __expf(e * drL[n]);
                float ph = e * diL[n];
                float v = (s < 64) ? ex * __cosf(ph) : ex * __sinf(ph);
                Vfrag[vbase + idx] = f2bf(v);
            }
        }
    } else {
        // ================= ln body (single-pass; verified R3-R8) =================
        float* Xs = (float*)smem;              // [256][65] flattened = 66560 B
        float* rs = (float*)(smem + 66560);    // [4][64]
        float* rq = rs + 256;                  // [4][64]
        int bx = bxg - 512;
        int b = bx >> 5, l0 = (bx & 31) << 6;
        const float* xb = x + (size_t)b * (Hh * (size_t)Ll) + l0;
        const float* tbp = tb + b * 256;
        int f4 = tid & 15, h0 = tid >> 4;
        #pragma unroll
        for (int i = 0; i < 16; ++i) {
            int h = i * 16 + h0;
            float4 v = *((const float4*)(xb + (size_t)h * Ll) + f4);
            float tv = tbp[h];
            Xs[h * 65 + f4 * 4 + 0] = v.x + tv;
            Xs[h * 65 + f4 * 4 + 1] = v.y + tv;
            Xs[h * 65 + f4 * 4 + 2] = v.z + tv;
            Xs[h * 65 + f4 * 4 + 3] = v.w + tv;
        }
        __syncthreads();
        int l = tid & 63, qd = tid >> 6;
        float sum = 0.f, ssq = 0.f;
        #pragma unroll 8
        for (int i = 0; i < 64; ++i) {
            float v = Xs[(qd * 64 + i) * 65 + l];
            sum += v; ssq = fmaf(v, v, ssq);
        }
        rs[qd * 64 + l] = sum; rq[qd * 64 + l] = ssq;
        __syncthreads();
        sum = rs[l] + rs[64 + l] + rs[128 + l] + rs[192 + l];
        ssq = rq[l] + rq[64 + l] + rq[128 + l] + rq[192 + l];
        float mean = sum * (1.f / 256.f);
        float var = fmaf(ssq, 1.f / 256.f, -mean * mean);
        float rstd = rsqrtf(var + 1e-5f);
        ushort_t* zp = zbf + (size_t)b * (Hh * (size_t)Ll) + l0 + l;
        #pragma unroll 8
        for (int i = 0; i < 64; ++i) {
            int h = qd * 64 + i;
            float v = Xs[h * 65 + l];
            zp[(size_t)h * Ll] = f2bf((v - mean) * rstd * ln_g[h] + ln_b[h]);
        }
    }
}

// ---------------- mega SSM v3: no Zs staging (z read direct, L2-hot) ----------------
// LDS 69632 -> 52224 B => 3 blocks/CU (was 2). z-tile (16 KB/block) is L2-resident:
// ~96 blocks/XCD x 16 KB = 1.5 MB << 4 MB L2, and ln just wrote it through L2.
// Scan: all 16 (qre,qim) prefetched to registers (fully unrolled, static idx) so the
// serial recurrence is pure-register -- LDS write/read may-alias no longer serializes it.
__global__ __launch_bounds__(256) void ssm_mega_kernel(
    const ushort_t* __restrict__ zbf,
    const float* __restrict__ drg, const float* __restrict__ dig, const float* __restrict__ Dv,
    const ushort_t* __restrict__ Mfrag, const ushort_t* __restrict__ Vfrag,
    ushort_t* __restrict__ ya)
{
    __shared__ ushort_t Ssf[64 * 136];
    __shared__ ushort_t Ssb[64 * 136];
    __shared__ float Qb[2 * 128 * 17];
    int tid = threadIdx.x, lane = tid & 63, w = tid >> 6;
    int q = lane >> 4, cl = lane & 15;
    int h = blockIdx.x, cb = blockIdx.y;
    int b0 = cb * 4;
    float dr0 = drg[h * 64 + lane], di0 = dig[h * 64 + lane];
    float ex128 = __expf(128.f * dr0);
    float w128r = ex128 * __cosf(128.f * di0);
    float w128i = ex128 * __sinf(128.f * di0);
    float Dh = Dv[h];
    const ushort_t* vbase = Vfrag + ((size_t)h << 14);
    const ushort_t* mbase0 = Mfrag + ((size_t)(h * 2) << 15);
    const ushort_t* mbase1 = Mfrag + ((size_t)(h * 2 + 1) << 15);
    // hoist Vandermonde A-fragments (bsub-invariant): 32 VGPR
    bf16x8 vfr[4][2];
    #pragma unroll
    for (int kc = 0; kc < 4; ++kc)
        #pragma unroll
        for (int i = 0; i < 2; ++i) {
            int mt = w * 2 + i;
            vfr[kc][i] = __builtin_bit_cast(bf16x8,
                *(const uint4v*)(vbase + (((mt * 4 + kc) * 64 + lane) << 3)));
        }
    #pragma unroll
    for (int bsub = 0; bsub < 4; ++bsub) {
        const ushort_t* ztb = zbf + ((size_t)((b0 + bsub) * 256 + h) << 11);
        f32x4 qa[2][2] = {};
        #pragma unroll
        for (int kc = 0; kc < 4; ++kc) {
            int kk = kc * 32 + q * 8;
            bf16x8 bz = __builtin_bit_cast(bf16x8,
                *(const uint4v*)(ztb + cl * 128 + kk));
            bf16x8 bzr = __builtin_bit_cast(bf16x8, rev8v(
                *(const uint4v*)(ztb + (15 - cl) * 128 + (120 - kk))));
            #pragma unroll
            for (int i = 0; i < 2; ++i) {
                qa[0][i] = __builtin_amdgcn_mfma_f32_16x16x32_bf16(vfr[kc][i], bz, qa[0][i], 0, 0, 0);
                qa[1][i] = __builtin_amdgcn_mfma_f32_16x16x32_bf16(vfr[kc][i], bzr, qa[1][i], 0, 0, 0);
            }
        }
        __syncthreads();   // previous scan's Qb reads complete
        #pragma unroll
        for (int d = 0; d < 2; ++d)
            #pragma unroll
            for (int i = 0; i < 2; ++i) {
                int mt = w * 2 + i;
                #pragma unroll
                for (int r = 0; r < 4; ++r)
                    Qb[d * 2176 + (mt * 16 + q * 4 + r) * 17 + cl] = qa[d][i][r];
            }
        __syncthreads();
        if (w < 2) {           // w=0: fwd scan, w=1: bwd scan (parallel waves)
            ushort_t* S = (w == 0) ? Ssf : Ssb;
            const float* Qp = Qb + w * 2176;
            float qr_[16], qi_[16];
            #pragma unroll
            for (int cc = 0; cc < 16; ++cc) {
                qr_[cc] = Qp[lane * 17 + cc];
                qi_[cc] = Qp[(64 + lane) * 17 + cc];
            }
            float sre = 0.f, sim = 0.f;
            #pragma unroll
            for (int cc = 0; cc < 16; ++cc) {
                S[(bsub * 16 + cc) * 136 + lane] = f2bf(sre);
                S[(bsub * 16 + cc) * 136 + 64 + lane] = f2bf(sim);
                float nre = fmaf(w128r, sre, fmaf(-w128i, sim, qr_[cc]));
                float nim = fmaf(w128r, sim, fmaf(w128i, sre, qi_[cc]));
                sre = nre; sim = nim;
            }
        }
        __syncthreads();
    }
    f32x4 accf[2][4] = {}, accb[2][4] = {};
    for (int kc = 0; kc < 8; ++kc) {
        int kk = (kc & 3) * 32 + q * 8;
        bf16x8 aff[2], afb[2];
        #pragma unroll
        for (int i = 0; i < 2; ++i) {
            int mt = w * 2 + i;
            aff[i] = __builtin_bit_cast(bf16x8, *(const uint4v*)(mbase0 + (((mt * 8 + kc) * 64 + lane) << 3)));
            afb[i] = __builtin_bit_cast(bf16x8, *(const uint4v*)(mbase1 + (((mt * 8 + kc) * 64 + lane) << 3)));
        }
        #pragma unroll
        for (int nt = 0; nt < 4; ++nt) {
            const ushort_t* ztn = zbf + ((size_t)((b0 + nt) * 256 + h) << 11);
            bf16x8 bff, bfb_;
            if (kc < 4) {
                bff  = __builtin_bit_cast(bf16x8, *(const uint4v*)(ztn + cl * 128 + kk));
                bfb_ = __builtin_bit_cast(bf16x8, rev8v(
                       *(const uint4v*)(ztn + (15 - cl) * 128 + (120 - kk))));
            } else {
                bff  = __builtin_bit_cast(bf16x8, *(const uint4v*)&Ssf[(nt * 16 + cl) * 136 + kk]);
                bfb_ = __builtin_bit_cast(bf16x8, *(const uint4v*)&Ssb[(nt * 16 + cl) * 136 + kk]);
            }
            #pragma unroll
            for (int i = 0; i < 2; ++i) {
                accf[i][nt] = __builtin_amdgcn_mfma_f32_16x16x32_bf16(aff[i], bff,  accf[i][nt], 0, 0, 0);
                accb[i][nt] = __builtin_amdgcn_mfma_f32_16x16x32_bf16(afb[i], bfb_, accb[i][nt], 0, 0, 0);
            }
        }
    }
    __syncthreads();           // conv reads of Ssf/Ssb done; reuse as Yf/Yb
    ushort_t* Yf = Ssf;
    ushort_t* Yb = Ssb;
    #pragma unroll
    for (int i = 0; i < 2; ++i) {
        int mt = w * 2 + i;
        #pragma unroll
        for (int nt = 0; nt < 4; ++nt) {
            int col = nt * 16 + cl;
            #pragma unroll
            for (int r = 0; r < 4; ++r) {
                int m = mt * 16 + q * 4 + r;
                Yf[col * 136 + m] = f2bf(accf[i][nt][r]);
                Yb[col * 136 + m] = f2bf(accb[i][nt][r]);
            }
        }
    }
    __syncthreads();
    for (int u = tid; u < 1024; u += 256) {
        int col = u >> 4, i0 = (u & 15) * 8;
        int bsub = col >> 4, c = col & 15;
        int colb = bsub * 16 + (15 - c);
        const ushort_t* ztb = zbf + ((size_t)((b0 + bsub) * 256 + h) << 11);
        union { uint4v v; ushort_t s8[8]; } uf, uz, ub, uo;
        uf.v = *(const uint4v*)&Yf[col * 136 + i0];
        uz.v = *(const uint4v*)(ztb + c * 128 + i0);
        ub.v = rev8v(*(const uint4v*)&Yb[colb * 136 + (120 - i0)]);
        #pragma unroll
        for (int j = 0; j < 8; ++j) {
            float v = bf2f(uf.s8[j]) + bf2f(ub.s8[j]) + Dh * bf2f(uz.s8[j]);
            uo.s8[j] = f2bf(gelu_tanh(v));
        }
        ushort_t* yrow = ya + ((size_t)((b0 + bsub) * 256 + h) << 11);
        *(uint4v*)(yrow + c * 128 + i0) = uo.v;
    }
}

// ---------------- GEMM1: g = gate(Wc @ [ya; feat] + bc + x + tb) ----------------
__global__ __launch_bounds__(256, 4) void gemm1_kernel(
    const ushort_t* __restrict__ ya, const float* __restrict__ feat,
    const float* __restrict__ x, const float* __restrict__ tb,
    const float* __restrict__ bc, const ushort_t* __restrict__ wcf,
    ushort_t* __restrict__ g)
{
    __shared__ __align__(16) ushort_t XT[64 * 48];
    int tid = threadIdx.x;
    int w = tid >> 6, lane = tid & 63;
    int bx = blockIdx.x;
    int b = bx >> 5;
    int l0 = (bx & 31) << 6;
    f32x4 acc[4][4] = {};
    int kk = tid >> 3, ng = tid & 7;
    for (int kc = 0; kc < 9; ++kc) {
        int k = kc * 32 + kk;
        union { uint4v v; ushort_t s[8]; } u;
        if (k < 256) {
            u.v = *(const uint4v*)(ya + ((size_t)(b * 256 + k) << 11) + l0 + ng * 8);
        } else {
            const float* src = feat + (size_t)(b * 32 + (k - 256)) * Ll + l0 + ng * 8;
            #pragma unroll
            for (int j = 0; j < 8; ++j) u.s[j] = f2bf(src[j]);
        }
        #pragma unroll
        for (int j = 0; j < 8; ++j) XT[(ng * 8 + j) * 48 + kk] = u.s[j];
        __syncthreads();
        bf16x8 af[4], bfr[4];
        #pragma unroll
        for (int i = 0; i < 4; ++i) {
            const ushort_t* p = wcf + ((size_t)((w * 4 + i) * 9 + kc) * 64 + lane) * 8;
            af[i] = __builtin_bit_cast(bf16x8, *(const uint4v*)p);
        }
        #pragma unroll
        for (int nt = 0; nt < 4; ++nt) {
            const ushort_t* p = &XT[(nt * 16 + (lane & 15)) * 48 + (lane >> 4) * 8];
            bfr[nt] = __builtin_bit_cast(bf16x8, *(const uint4v*)p);
        }
        #pragma unroll
        for (int i = 0; i < 4; ++i)
            #pragma unroll
            for (int nt = 0; nt < 4; ++nt)
                acc[i][nt] = __builtin_amdgcn_mfma_f32_16x16x32_bf16(af[i], bfr[nt], acc[i][nt], 0, 0, 0);
        __syncthreads();
    }
    int q = lane >> 4, nl = lane & 15;
    #pragma unroll
    for (int i = 0; i < 4; ++i) {
        #pragma unroll
        for (int nt = 0; nt < 4; ++nt) {
            int n = l0 + nt * 16 + nl;
            #pragma unroll
            for (int r = 0; r < 4; ++r) {
                int m = (w * 4 + i) * 16 + q * 4 + r;
                size_t oi = (size_t)(b * 256 + m) * Ll + n;
                float v = acc[i][nt][r] + bc[m] + tb[b * 256 + m] + x[oi];
                g[oi] = f2bf(gate_fn(v));
            }
        }
    }
}

// ---------------- GEMM2: o1 = W1@g + b1 + x ; o2 = W2@g + b2 ----------------
__global__ __launch_bounds__(256, 4) void gemm2_kernel(
    const ushort_t* __restrict__ g, const float* __restrict__ x,
    const float* __restrict__ b12, const ushort_t* __restrict__ w12f,
    float* __restrict__ out)
{
    __shared__ __align__(16) ushort_t XT[64 * 48];
    int tid = threadIdx.x;
    int w = tid >> 6, lane = tid & 63;
    int bx = blockIdx.x;
    int half = blockIdx.y;
    int b = bx >> 5;
    int l0 = (bx & 31) << 6;
    f32x4 acc[4][4] = {};
    int kk = tid >> 3, ng = tid & 7;
    for (int kc = 0; kc < 8; ++kc) {
        int k = kc * 32 + kk;
        union { uint4v v; ushort_t s[8]; } u;
        u.v = *(const uint4v*)(g + (size_t)(b * 256 + k) * Ll + l0 + ng * 8);
        #pragma unroll
        for (int j = 0; j < 8; ++j) XT[(ng * 8 + j) * 48 + kk] = u.s[j];
        __syncthreads();
        bf16x8 af[4], bfr[4];
        #pragma unroll
        for (int i = 0; i < 4; ++i) {
            int mtg = half * 16 + w * 4 + i;
            const ushort_t* p = w12f + ((size_t)(mtg * 8 + kc) * 64 + lane) * 8;
            af[i] = __builtin_bit_cast(bf16x8, *(const uint4v*)p);
        }
        #pragma unroll
        for (int nt = 0; nt < 4; ++nt) {
            const ushort_t* p = &XT[(nt * 16 + (lane & 15)) * 48 + (lane >> 4) * 8];
            bfr[nt] = __builtin_bit_cast(bf16x8, *(const uint4v*)p);
        }
        #pragma unroll
        for (int i = 0; i < 4; ++i)
            #pragma unroll
            for (int nt = 0; nt < 4; ++nt)
                acc[i][nt] = __builtin_amdgcn_mfma_f32_16x16x32_bf16(af[i], bfr[nt], acc[i][nt], 0, 0, 0);
        __syncthreads();
    }
    int q = lane >> 4, nl = lane & 15;
    #pragma unroll
    for (int i = 0; i < 4; ++i) {
        #pragma unroll
        for (int nt = 0; nt < 4; ++nt) {
            int n = l0 + nt * 16 + nl;
            #pragma unroll
            for (int r = 0; r < 4; ++r) {
                int m = (w * 4 + i) * 16 + q * 4 + r;
                size_t oi = (size_t)(b * 256 + m) * Ll + n;
                float v = acc[i][nt][r] + b12[half * 256 + m];
                if (half == 0) out[oi] = v + x[oi];
                else out[(size_t)BHL + oi] = v;
            }
        }
    }
}

extern "C" void kernel_launch(void* const* d_in, const int* in_sizes, int n_in,
                              void* d_out, int out_size, void* d_ws, size_t ws_size,
                              hipStream_t stream) {
    const float* x      = (const float*)d_in[0];
    const float* t      = (const float*)d_in[1];
    const float* feat   = (const float*)d_in[2];
    const float* Wt     = (const float*)d_in[3];
    const float* bt     = (const float*)d_in[4];
    const float* ln_g   = (const float*)d_in[5];
    const float* ln_b   = (const float*)d_in[6];
    const float* log_dt = (const float*)d_in[7];
    const float* logA   = (const float*)d_in[8];
    const float* Aimg   = (const float*)d_in[9];
    const float* C_re   = (const float*)d_in[10];
    const float* C_im   = (const float*)d_in[11];
    const float* Dv     = (const float*)d_in[12];
    const float* Wout   = (const float*)d_in[13];
    const float* bout   = (const float*)d_in[14];
    const float* W1     = (const float*)d_in[15];
    const float* b1     = (const float*)d_in[16];
    const float* W2     = (const float*)d_in[17];
    const float* b2     = (const float*)d_in[18];
    const float* Wf     = (const float*)d_in[19];
    const float* bfb    = (const float*)d_in[20];

    // d_out (128 MiB): zbf [0,32Mi) | ya [32,64Mi) ; later fully overwritten by out
    char* ob = (char*)d_out;
    ushort_t* zbf = (ushort_t*)ob;
    ushort_t* yab = (ushort_t*)(ob + 33554432);
    float*    out = (float*)d_out;

    // ws: Mfrag 32 MiB (aliased by g after mega) | Vfrag 8 MiB | small tables
    char* ws = (char*)d_ws;
    ushort_t* Mfrag = (ushort_t*)ws;
    ushort_t* gbuf  = (ushort_t*)ws;                  // alias: g overwrites Mfrag (dead by gemm1)
    ushort_t* Vfrag = (ushort_t*)(ws + 33554432);
    char* ws2 = ws + 33554432 + 8388608;
    float* tb   = (float*)ws2;
    float* drg  = (float*)(ws2 + 32768);
    float* dig  = (float*)(ws2 + 98304);
    float* bc   = (float*)(ws2 + 163840);
    float* b12  = (float*)(ws2 + 164864);
    ushort_t* wcf  = (ushort_t*)(ws2 + 166912);
    ushort_t* w12f = (ushort_t*)(ws2 + 314368);

    prep_kernel<<<96, 256, 0, stream>>>(t, Wt, bt, Wout, Wf, bout, bfb, W1, b1, W2, b2,
                                        tb, bc, b12, wcf, w12f);
    prep2ln_kernel<<<1536, 256, 0, stream>>>(log_dt, logA, Aimg, C_re, C_im, drg, dig,
                                             Mfrag, Vfrag, x, tb, ln_g, ln_b, zbf);
    ssm_mega_kernel<<<dim3(256, 8), 256, 0, stream>>>(zbf, drg, dig, Dv, Mfrag, Vfrag, yab);
    gemm1_kernel<<<1024, 256, 0, stream>>>(yab, feat, x, tb, bc, wcf, gbuf);
    gemm2_kernel<<<dim3(1024, 2), 256, 0, stream>>>(gbuf, x, b12, w12f, out);
}

// Round 11
// 398.221 us; speedup vs baseline: 1.0967x; 1.0967x over previous
//
#include <hip/hip_runtime.h>

typedef unsigned short ushort_t;

#define Bb 32
#define Hh 256
#define Ll 2048
#define Nn 64
#define BHL 16777216

typedef __bf16 bf16x8 __attribute__((ext_vector_type(8)));
typedef float f32x4 __attribute__((ext_vector_type(4)));
typedef unsigned int uint4v __attribute__((ext_vector_type(4)));

__device__ __forceinline__ ushort_t f2bf(float f) {
    unsigned int u = __float_as_uint(f);
    unsigned int r = ((u >> 16) & 1u) + 0x7fffu;
    return (ushort_t)((u + r) >> 16);
}
__device__ __forceinline__ float bf2f(ushort_t h) {
    return __uint_as_float(((unsigned int)h) << 16);
}
__device__ __forceinline__ float gelu_tanh(float v) {
    float u = 0.7978845608028654f * fmaf(0.044715f * v, v * v, v);
    float e = __expf(2.f * u);
    float th = 1.f - 2.f / (e + 1.f);
    return 0.5f * v * (1.f + th);
}
__device__ __forceinline__ float gate_fn(float v) {
    float sg = 1.f / (1.f + __expf(-v));
    float e2 = __expf(2.f * v);
    float th = 1.f - 2.f / (e2 + 1.f);
    return th * sg;
}
__device__ __forceinline__ uint4v rev8v(uint4v a) {
    union { uint4v v; ushort_t s8[8]; } x, y;
    x.v = a;
    #pragma unroll
    for (int j = 0; j < 8; ++j) y.s8[j] = x.s8[7 - j];
    return y.v;
}

// ---------------- prep: tb GEMM + weight fragment repack ----------------
__global__ __launch_bounds__(256) void prep_kernel(
    const float* __restrict__ t, const float* __restrict__ Wt, const float* __restrict__ bt,
    const float* __restrict__ Wout, const float* __restrict__ Wf,
    const float* __restrict__ bout, const float* __restrict__ bfb,
    const float* __restrict__ W1, const float* __restrict__ b1,
    const float* __restrict__ W2, const float* __restrict__ b2,
    float* __restrict__ tb, float* __restrict__ bc, float* __restrict__ b12,
    ushort_t* __restrict__ wcf, ushort_t* __restrict__ w12f)
{
    int bx = blockIdx.x, tid = threadIdx.x;
    __shared__ float trow[256];
    if (bx < 32) {
        trow[tid] = t[bx * 256 + tid];
        __syncthreads();
        float acc = bt[tid];
        #pragma unroll 4
        for (int hh = 0; hh < 256; ++hh) acc = fmaf(trow[hh], Wt[tid * 256 + hh], acc);
        tb[bx * 256 + tid] = acc;
    } else if (bx < 64) {
        int gt = (bx - 32) * 256 + tid;       // 0..8191
        if (gt < 256) bc[gt] = bout[gt] + bfb[gt];
        if (gt < 512) b12[gt] = (gt < 256) ? b1[gt] : b2[gt - 256];
        // Wc_frag: 16 mtiles x 9 kchunks x 64 lanes x 8  (K=288: [Wout | Wf])
        for (int fg = gt; fg < 9216; fg += 8192) {
            int mt = fg / 576, rem = fg % 576;
            int kc = rem >> 6, lane = rem & 63;
            int m = mt * 16 + (lane & 15);
            int kb = kc * 32 + (lane >> 4) * 8;
            #pragma unroll
            for (int j = 0; j < 8; ++j) {
                int k = kb + j;
                float v = (k < 256) ? Wout[m * 256 + k] : Wf[m * 32 + (k - 256)];
                wcf[(size_t)fg * 8 + j] = f2bf(v);
            }
        }
    } else {
        int gt = (bx - 64) * 256 + tid;       // 0..8191
        // W12_frag: 32 mtiles x 8 kchunks x 64 lanes x 8  (M=512: [W1 ; W2])
        for (int fg = gt; fg < 16384; fg += 8192) {
            int mt = fg >> 9, rem = fg & 511;
            int kc = rem >> 6, lane = rem & 63;
            int m = mt * 16 + (lane & 15);
            int kb = kc * 32 + (lane >> 4) * 8;
            #pragma unroll
            for (int j = 0; j < 8; ++j) {
                int k = kb + j;
                float v = (m < 256) ? W1[m * 256 + k] : W2[(m - 256) * 256 + k];
                w12f[(size_t)fg * 8 + j] = f2bf(v);
            }
        }
    }
}

// ---------------- MERGED prep2 + ln (measured neutral vs split; saves a launch) ----------------
// blocks [0,512): prep2 ; blocks [512,1536): ln
__global__ __launch_bounds__(256) void prep2ln_kernel(
    const float* __restrict__ log_dt, const float* __restrict__ logA, const float* __restrict__ Aimg,
    const float* __restrict__ C_re, const float* __restrict__ C_im,
    float* __restrict__ drg, float* __restrict__ dig,
    ushort_t* __restrict__ Mfrag, ushort_t* __restrict__ Vfrag,
    const float* __restrict__ x, const float* __restrict__ tb,
    const float* __restrict__ ln_g, const float* __restrict__ ln_b,
    ushort_t* __restrict__ zbf)
{
    __shared__ __align__(16) char smem[68608];
    int bxg = blockIdx.x, tid = threadIdx.x;
    if (bxg < 512) {
        // ================= prep2 body =================
        float* drL = (float*)smem;             // 64
        float* diL = drL + 64;                 // 64
        float* crL = drL + 128;                // 64
        float* ciL = drL + 192;                // 64
        float* ktab = drL + 256;               // 128
        ushort_t* bndL = (ushort_t*)(smem + 1536);  // 128*128 ushort = 32768 B
        int bx = bxg;
        int h = bx >> 1, dir = bx & 1;
        if (tid < 64) {
            int n = tid;
            int idx = h * 64 + n;
            float dt = __expf(log_dt[h]);
            float Ar = -__expf(logA[idx]);
            float Ai = Aimg[idx];
            float dr = dt * Ar, di = dt * Ai;
            float er = __expf(dr);
            float wr_ = er * __cosf(di), wi_ = er * __sinf(di);
            float nr = wr_ - 1.f, ni = wi_;
            float inv = 1.f / (Ar * Ar + Ai * Ai);
            float qr = (nr * Ar + ni * Ai) * inv;
            float qi = (ni * Ar - nr * Ai) * inv;
            float cr = C_re[dir * 16384 + idx], ci = C_im[dir * 16384 + idx];
            drL[n] = dr; diL[n] = di;
            crL[n] = 2.f * (cr * qr - ci * qi);
            ciL[n] = 2.f * (cr * qi + ci * qr);
            if (dir == 0) { drg[idx] = dr; dig[idx] = di; }
        }
        __syncthreads();
        if (tid < 128) {
            int i = tid;
            float e = (float)(i + 1 - dir);
            #pragma unroll 4
            for (int n = 0; n < 64; ++n) {
                float ex = __expf(e * drL[n]);
                float ph = e * diL[n];
                float pr = ex * __cosf(ph), pi = ex * __sinf(ph);
                bndL[i * 128 + n]      = f2bf(crL[n] * pr - ciL[n] * pi);
                bndL[i * 128 + 64 + n] = f2bf(-(crL[n] * pi + ciL[n] * pr));
            }
        } else {
            int d = tid - 128;
            float e = (float)d;
            float acc = 0.f;
            #pragma unroll 4
            for (int n = 0; n < 64; ++n) {
                float ex = __expf(e * drL[n]);
                float ph = e * diL[n];
                acc += crL[n] * (ex * __cosf(ph)) - ciL[n] * (ex * __sinf(ph));
            }
            ktab[d] = acc;
        }
        __syncthreads();
        size_t base = (size_t)bx << 15;
        for (int idx = tid; idx < 32768; idx += 256) {
            int j = idx & 7, lane = (idx >> 3) & 63, kc = (idx >> 9) & 7, mt = idx >> 12;
            int m = mt * 16 + (lane & 15);
            int k = kc * 32 + (lane >> 4) * 8 + j;
            float v;
            if (k < 128) {
                int d = m - k - dir;
                v = (d >= 0) ? ktab[d] : 0.f;
            } else {
                v = bf2f(bndL[m * 128 + (k - 128)]);
            }
            Mfrag[base + idx] = f2bf(v);
        }
        if (dir == 0) {
            size_t vbase = (size_t)h << 14;
            for (int idx = tid; idx < 16384; idx += 256) {
                int j = idx & 7, lane = (idx >> 3) & 63, kc = (idx >> 9) & 3, mt = idx >> 11;
                int s = mt * 16 + (lane & 15);
                int k = kc * 32 + (lane >> 4) * 8 + j;
                int n = s & 63;
                float e = (float)(127 - k);
                float ex = __expf(e * drL[n]);
                float ph = e * diL[n];
                float v = (s < 64) ? ex * __cosf(ph) : ex * __sinf(ph);
                Vfrag[vbase + idx] = f2bf(v);
            }
        }
    } else {
        // ================= ln body (single-pass; verified R3-R9) =================
        float* Xs = (float*)smem;              // [256][65] flattened = 66560 B
        float* rs = (float*)(smem + 66560);    // [4][64]
        float* rq = rs + 256;                  // [4][64]
        int bx = bxg - 512;
        int b = bx >> 5, l0 = (bx & 31) << 6;
        const float* xb = x + (size_t)b * (Hh * (size_t)Ll) + l0;
        const float* tbp = tb + b * 256;
        int f4 = tid & 15, h0 = tid >> 4;
        #pragma unroll
        for (int i = 0; i < 16; ++i) {
            int h = i * 16 + h0;
            float4 v = *((const float4*)(xb + (size_t)h * Ll) + f4);
            float tv = tbp[h];
            Xs[h * 65 + f4 * 4 + 0] = v.x + tv;
            Xs[h * 65 + f4 * 4 + 1] = v.y + tv;
            Xs[h * 65 + f4 * 4 + 2] = v.z + tv;
            Xs[h * 65 + f4 * 4 + 3] = v.w + tv;
        }
        __syncthreads();
        int l = tid & 63, qd = tid >> 6;
        float sum = 0.f, ssq = 0.f;
        #pragma unroll 8
        for (int i = 0; i < 64; ++i) {
            float v = Xs[(qd * 64 + i) * 65 + l];
            sum += v; ssq = fmaf(v, v, ssq);
        }
        rs[qd * 64 + l] = sum; rq[qd * 64 + l] = ssq;
        __syncthreads();
        sum = rs[l] + rs[64 + l] + rs[128 + l] + rs[192 + l];
        ssq = rq[l] + rq[64 + l] + rq[128 + l] + rq[192 + l];
        float mean = sum * (1.f / 256.f);
        float var = fmaf(ssq, 1.f / 256.f, -mean * mean);
        float rstd = rsqrtf(var + 1e-5f);
        ushort_t* zp = zbf + (size_t)b * (Hh * (size_t)Ll) + l0 + l;
        #pragma unroll 8
        for (int i = 0; i < 64; ++i) {
            int h = qd * 64 + i;
            float v = Xs[h * 65 + l];
            zp[(size_t)h * Ll] = f2bf((v - mean) * rstd * ln_g[h] + ln_b[h]);
        }
    }
}

// ---------------- mega SSM (R8 structure: Zs staged, coalesced; grid 256x8) ----------------
// R9 falsified direct-global z reads: Zs is the coalescing transformer for the
// column-access MFMA pattern (deleting it: FETCH 58->104 MB, ssm 75->107 us).
// Kept from v3: scan prefetches all 16 (qre,qim) into registers (static idx) so the
// serial recurrence is pure-register (Qb/Ssf may-alias can't serialize it).
__global__ __launch_bounds__(256) void ssm_mega_kernel(
    const ushort_t* __restrict__ zbf,
    const float* __restrict__ drg, const float* __restrict__ dig, const float* __restrict__ Dv,
    const ushort_t* __restrict__ Mfrag, const ushort_t* __restrict__ Vfrag,
    ushort_t* __restrict__ ya)
{
    __shared__ ushort_t Zs[64 * 136];
    __shared__ ushort_t Ssf[64 * 136];
    __shared__ ushort_t Ssb[64 * 136];
    __shared__ float Qb[2 * 128 * 17];
    int tid = threadIdx.x, lane = tid & 63, w = tid >> 6;
    int q = lane >> 4, cl = lane & 15;
    int h = blockIdx.x, cb = blockIdx.y;
    int b0 = cb * 4;
    for (int i = tid; i < 1024; i += 256) {
        int bsub = i >> 8, t8 = (i & 255) * 8;
        const ushort_t* zrow = zbf + ((size_t)((b0 + bsub) * 256 + h) << 11);
        *(uint4v*)&Zs[(bsub * 16 + (t8 >> 7)) * 136 + (t8 & 127)] = *(const uint4v*)(zrow + t8);
    }
    float dr0 = drg[h * 64 + lane], di0 = dig[h * 64 + lane];
    float ex128 = __expf(128.f * dr0);
    float w128r = ex128 * __cosf(128.f * di0);
    float w128i = ex128 * __sinf(128.f * di0);
    float Dh = Dv[h];
    const ushort_t* vbase = Vfrag + ((size_t)h << 14);
    const ushort_t* mbase0 = Mfrag + ((size_t)(h * 2) << 15);
    const ushort_t* mbase1 = Mfrag + ((size_t)(h * 2 + 1) << 15);
    // hoist Vandermonde A-fragments (bsub-invariant): 32 VGPR
    bf16x8 vfr[4][2];
    #pragma unroll
    for (int kc = 0; kc < 4; ++kc)
        #pragma unroll
        for (int i = 0; i < 2; ++i) {
            int mt = w * 2 + i;
            vfr[kc][i] = __builtin_bit_cast(bf16x8,
                *(const uint4v*)(vbase + (((mt * 4 + kc) * 64 + lane) << 3)));
        }
    __syncthreads();
    for (int bsub = 0; bsub < 4; ++bsub) {
        f32x4 qa[2][2] = {};
        #pragma unroll
        for (int kc = 0; kc < 4; ++kc) {
            int kk = kc * 32 + q * 8;
            bf16x8 bz = __builtin_bit_cast(bf16x8,
                *(const uint4v*)&Zs[(bsub * 16 + cl) * 136 + kk]);
            bf16x8 bzr = __builtin_bit_cast(bf16x8, rev8v(
                *(const uint4v*)&Zs[(bsub * 16 + (15 - cl)) * 136 + (120 - kk)]));
            #pragma unroll
            for (int i = 0; i < 2; ++i) {
                qa[0][i] = __builtin_amdgcn_mfma_f32_16x16x32_bf16(vfr[kc][i], bz, qa[0][i], 0, 0, 0);
                qa[1][i] = __builtin_amdgcn_mfma_f32_16x16x32_bf16(vfr[kc][i], bzr, qa[1][i], 0, 0, 0);
            }
        }
        __syncthreads();
        #pragma unroll
        for (int d = 0; d < 2; ++d)
            #pragma unroll
            for (int i = 0; i < 2; ++i) {
                int mt = w * 2 + i;
                #pragma unroll
                for (int r = 0; r < 4; ++r)
                    Qb[d * 2176 + (mt * 16 + q * 4 + r) * 17 + cl] = qa[d][i][r];
            }
        __syncthreads();
        if (w < 2) {
            ushort_t* S = (w == 0) ? Ssf : Ssb;
            const float* Qp = Qb + w * 2176;
            float qr_[16], qi_[16];
            #pragma unroll
            for (int cc = 0; cc < 16; ++cc) {
                qr_[cc] = Qp[lane * 17 + cc];
                qi_[cc] = Qp[(64 + lane) * 17 + cc];
            }
            float sre = 0.f, sim = 0.f;
            #pragma unroll
            for (int cc = 0; cc < 16; ++cc) {
                S[(bsub * 16 + cc) * 136 + lane] = f2bf(sre);
                S[(bsub * 16 + cc) * 136 + 64 + lane] = f2bf(sim);
                float nre = fmaf(w128r, sre, fmaf(-w128i, sim, qr_[cc]));
                float nim = fmaf(w128r, sim, fmaf(w128i, sre, qi_[cc]));
                sre = nre; sim = nim;
            }
        }
        __syncthreads();
    }
    f32x4 accf[2][4] = {}, accb[2][4] = {};
    for (int kc = 0; kc < 8; ++kc) {
        int kk = (kc & 3) * 32 + q * 8;
        bf16x8 aff[2], afb[2];
        #pragma unroll
        for (int i = 0; i < 2; ++i) {
            int mt = w * 2 + i;
            aff[i] = __builtin_bit_cast(bf16x8, *(const uint4v*)(mbase0 + (((mt * 8 + kc) * 64 + lane) << 3)));
            afb[i] = __builtin_bit_cast(bf16x8, *(const uint4v*)(mbase1 + (((mt * 8 + kc) * 64 + lane) << 3)));
        }
        #pragma unroll
        for (int nt = 0; nt < 4; ++nt) {
            bf16x8 bff, bfb_;
            if (kc < 4) {
                bff  = __builtin_bit_cast(bf16x8, *(const uint4v*)&Zs[(nt * 16 + cl) * 136 + kk]);
                bfb_ = __builtin_bit_cast(bf16x8, rev8v(
                       *(const uint4v*)&Zs[(nt * 16 + (15 - cl)) * 136 + (120 - kk)]));
            } else {
                bff  = __builtin_bit_cast(bf16x8, *(const uint4v*)&Ssf[(nt * 16 + cl) * 136 + kk]);
                bfb_ = __builtin_bit_cast(bf16x8, *(const uint4v*)&Ssb[(nt * 16 + cl) * 136 + kk]);
            }
            #pragma unroll
            for (int i = 0; i < 2; ++i) {
                accf[i][nt] = __builtin_amdgcn_mfma_f32_16x16x32_bf16(aff[i], bff,  accf[i][nt], 0, 0, 0);
                accb[i][nt] = __builtin_amdgcn_mfma_f32_16x16x32_bf16(afb[i], bfb_, accb[i][nt], 0, 0, 0);
            }
        }
    }
    __syncthreads();
    ushort_t* Yf = Ssf;
    ushort_t* Yb = Ssb;
    #pragma unroll
    for (int i = 0; i < 2; ++i) {
        int mt = w * 2 + i;
        #pragma unroll
        for (int nt = 0; nt < 4; ++nt) {
            int col = nt * 16 + cl;
            #pragma unroll
            for (int r = 0; r < 4; ++r) {
                int m = mt * 16 + q * 4 + r;
                Yf[col * 136 + m] = f2bf(accf[i][nt][r]);
                Yb[col * 136 + m] = f2bf(accb[i][nt][r]);
            }
        }
    }
    __syncthreads();
    for (int u = tid; u < 1024; u += 256) {
        int col = u >> 4, i0 = (u & 15) * 8;
        int bsub = col >> 4, c = col & 15;
        int colb = bsub * 16 + (15 - c);
        union { uint4v v; ushort_t s8[8]; } uf, uz, ub, uo;
        uf.v = *(const uint4v*)&Yf[col * 136 + i0];
        uz.v = *(const uint4v*)&Zs[col * 136 + i0];
        ub.v = rev8v(*(const uint4v*)&Yb[colb * 136 + (120 - i0)]);
        #pragma unroll
        for (int j = 0; j < 8; ++j) {
            float v = bf2f(uf.s8[j]) + bf2f(ub.s8[j]) + Dh * bf2f(uz.s8[j]);
            uo.s8[j] = f2bf(gelu_tanh(v));
        }
        ushort_t* yrow = ya + ((size_t)((b0 + bsub) * 256 + h) << 11);
        *(uint4v*)(yrow + c * 128 + i0) = uo.v;
    }
}

// ---------------- GEMM1: g = gate(Wc @ [ya; feat] + bc + x + tb) ----------------
__global__ __launch_bounds__(256, 4) void gemm1_kernel(
    const ushort_t* __restrict__ ya, const float* __restrict__ feat,
    const float* __restrict__ x, const float* __restrict__ tb,
    const float* __restrict__ bc, const ushort_t* __restrict__ wcf,
    ushort_t* __restrict__ g)
{
    __shared__ __align__(16) ushort_t XT[64 * 48];
    int tid = threadIdx.x;
    int w = tid >> 6, lane = tid & 63;
    int bx = blockIdx.x;
    int b = bx >> 5;
    int l0 = (bx & 31) << 6;
    f32x4 acc[4][4] = {};
    int kk = tid >> 3, ng = tid & 7;
    for (int kc = 0; kc < 9; ++kc) {
        int k = kc * 32 + kk;
        union { uint4v v; ushort_t s[8]; } u;
        if (k < 256) {
            u.v = *(const uint4v*)(ya + ((size_t)(b * 256 + k) << 11) + l0 + ng * 8);
        } else {
            const float* src = feat + (size_t)(b * 32 + (k - 256)) * Ll + l0 + ng * 8;
            #pragma unroll
            for (int j = 0; j < 8; ++j) u.s[j] = f2bf(src[j]);
        }
        #pragma unroll
        for (int j = 0; j < 8; ++j) XT[(ng * 8 + j) * 48 + kk] = u.s[j];
        __syncthreads();
        bf16x8 af[4], bfr[4];
        #pragma unroll
        for (int i = 0; i < 4; ++i) {
            const ushort_t* p = wcf + ((size_t)((w * 4 + i) * 9 + kc) * 64 + lane) * 8;
            af[i] = __builtin_bit_cast(bf16x8, *(const uint4v*)p);
        }
        #pragma unroll
        for (int nt = 0; nt < 4; ++nt) {
            const ushort_t* p = &XT[(nt * 16 + (lane & 15)) * 48 + (lane >> 4) * 8];
            bfr[nt] = __builtin_bit_cast(bf16x8, *(const uint4v*)p);
        }
        #pragma unroll
        for (int i = 0; i < 4; ++i)
            #pragma unroll
            for (int nt = 0; nt < 4; ++nt)
                acc[i][nt] = __builtin_amdgcn_mfma_f32_16x16x32_bf16(af[i], bfr[nt], acc[i][nt], 0, 0, 0);
        __syncthreads();
    }
    int q = lane >> 4, nl = lane & 15;
    #pragma unroll
    for (int i = 0; i < 4; ++i) {
        #pragma unroll
        for (int nt = 0; nt < 4; ++nt) {
            int n = l0 + nt * 16 + nl;
            #pragma unroll
            for (int r = 0; r < 4; ++r) {
                int m = (w * 4 + i) * 16 + q * 4 + r;
                size_t oi = (size_t)(b * 256 + m) * Ll + n;
                float v = acc[i][nt][r] + bc[m] + tb[b * 256 + m] + x[oi];
                g[oi] = f2bf(gate_fn(v));
            }
        }
    }
}

// ---------------- GEMM2: o1 = W1@g + b1 + x ; o2 = W2@g + b2 ----------------
__global__ __launch_bounds__(256, 4) void gemm2_kernel(
    const ushort_t* __restrict__ g, const float* __restrict__ x,
    const float* __restrict__ b12, const ushort_t* __restrict__ w12f,
    float* __restrict__ out)
{
    __shared__ __align__(16) ushort_t XT[64 * 48];
    int tid = threadIdx.x;
    int w = tid >> 6, lane = tid & 63;
    int bx = blockIdx.x;
    int half = blockIdx.y;
    int b = bx >> 5;
    int l0 = (bx & 31) << 6;
    f32x4 acc[4][4] = {};
    int kk = tid >> 3, ng = tid & 7;
    for (int kc = 0; kc < 8; ++kc) {
        int k = kc * 32 + kk;
        union { uint4v v; ushort_t s[8]; } u;
        u.v = *(const uint4v*)(g + (size_t)(b * 256 + k) * Ll + l0 + ng * 8);
        #pragma unroll
        for (int j = 0; j < 8; ++j) XT[(ng * 8 + j) * 48 + kk] = u.s[j];
        __syncthreads();
        bf16x8 af[4], bfr[4];
        #pragma unroll
        for (int i = 0; i < 4; ++i) {
            int mtg = half * 16 + w * 4 + i;
            const ushort_t* p = w12f + ((size_t)(mtg * 8 + kc) * 64 + lane) * 8;
            af[i] = __builtin_bit_cast(bf16x8, *(const uint4v*)p);
        }
        #pragma unroll
        for (int nt = 0; nt < 4; ++nt) {
            const ushort_t* p = &XT[(nt * 16 + (lane & 15)) * 48 + (lane >> 4) * 8];
            bfr[nt] = __builtin_bit_cast(bf16x8, *(const uint4v*)p);
        }
        #pragma unroll
        for (int i = 0; i < 4; ++i)
            #pragma unroll
            for (int nt = 0; nt < 4; ++nt)
                acc[i][nt] = __builtin_amdgcn_mfma_f32_16x16x32_bf16(af[i], bfr[nt], acc[i][nt], 0, 0, 0);
        __syncthreads();
    }
    int q = lane >> 4, nl = lane & 15;
    #pragma unroll
    for (int i = 0; i < 4; ++i) {
        #pragma unroll
        for (int nt = 0; nt < 4; ++nt) {
            int n = l0 + nt * 16 + nl;
            #pragma unroll
            for (int r = 0; r < 4; ++r) {
                int m = (w * 4 + i) * 16 + q * 4 + r;
                size_t oi = (size_t)(b * 256 + m) * Ll + n;
                float v = acc[i][nt][r] + b12[half * 256 + m];
                if (half == 0) out[oi] = v + x[oi];
                else out[(size_t)BHL + oi] = v;
            }
        }
    }
}

extern "C" void kernel_launch(void* const* d_in, const int* in_sizes, int n_in,
                              void* d_out, int out_size, void* d_ws, size_t ws_size,
                              hipStream_t stream) {
    const float* x      = (const float*)d_in[0];
    const float* t      = (const float*)d_in[1];
    const float* feat   = (const float*)d_in[2];
    const float* Wt     = (const float*)d_in[3];
    const float* bt     = (const float*)d_in[4];
    const float* ln_g   = (const float*)d_in[5];
    const float* ln_b   = (const float*)d_in[6];
    const float* log_dt = (const float*)d_in[7];
    const float* logA   = (const float*)d_in[8];
    const float* Aimg   = (const float*)d_in[9];
    const float* C_re   = (const float*)d_in[10];
    const float* C_im   = (const float*)d_in[11];
    const float* Dv     = (const float*)d_in[12];
    const float* Wout   = (const float*)d_in[13];
    const float* bout   = (const float*)d_in[14];
    const float* W1     = (const float*)d_in[15];
    const float* b1     = (const float*)d_in[16];
    const float* W2     = (const float*)d_in[17];
    const float* b2     = (const float*)d_in[18];
    const float* Wf     = (const float*)d_in[19];
    const float* bfb    = (const float*)d_in[20];

    // d_out (128 MiB): zbf [0,32Mi) | ya [32,64Mi) ; later fully overwritten by out
    char* ob = (char*)d_out;
    ushort_t* zbf = (ushort_t*)ob;
    ushort_t* yab = (ushort_t*)(ob + 33554432);
    float*    out = (float*)d_out;

    // ws: Mfrag 32 MiB (aliased by g after mega) | Vfrag 8 MiB | small tables
    char* ws = (char*)d_ws;
    ushort_t* Mfrag = (ushort_t*)ws;
    ushort_t* gbuf  = (ushort_t*)ws;                  // alias: g overwrites Mfrag (dead by gemm1)
    ushort_t* Vfrag = (ushort_t*)(ws + 33554432);
    char* ws2 = ws + 33554432 + 8388608;
    float* tb   = (float*)ws2;
    float* drg  = (float*)(ws2 + 32768);
    float* dig  = (float*)(ws2 + 98304);
    float* bc   = (float*)(ws2 + 163840);
    float* b12  = (float*)(ws2 + 164864);
    ushort_t* wcf  = (ushort_t*)(ws2 + 166912);
    ushort_t* w12f = (ushort_t*)(ws2 + 314368);

    prep_kernel<<<96, 256, 0, stream>>>(t, Wt, bt, Wout, Wf, bout, bfb, W1, b1, W2, b2,
                                        tb, bc, b12, wcf, w12f);
    prep2ln_kernel<<<1536, 256, 0, stream>>>(log_dt, logA, Aimg, C_re, C_im, drg, dig,
                                             Mfrag, Vfrag, x, tb, ln_g, ln_b, zbf);
    ssm_mega_kernel<<<dim3(256, 8), 256, 0, stream>>>(zbf, drg, dig, Dv, Mfrag, Vfrag, yab);
    gemm1_kernel<<<1024, 256, 0, stream>>>(yab, feat, x, tb, bc, wcf, gbuf);
    gemm2_kernel<<<dim3(1024, 2), 256, 0, stream>>>(gbuf, x, b12, w12f, out);
}

// Round 12
// 397.046 us; speedup vs baseline: 1.0999x; 1.0030x over previous
//
#include <hip/hip_runtime.h>

typedef unsigned short ushort_t;

#define Bb 32
#define Hh 256
#define Ll 2048
#define Nn 64
#define BHL 16777216

typedef __bf16 bf16x8 __attribute__((ext_vector_type(8)));
typedef float f32x4 __attribute__((ext_vector_type(4)));
typedef unsigned int uint4v __attribute__((ext_vector_type(4)));

__device__ __forceinline__ ushort_t f2bf(float f) {
    unsigned int u = __float_as_uint(f);
    unsigned int r = ((u >> 16) & 1u) + 0x7fffu;
    return (ushort_t)((u + r) >> 16);
}
__device__ __forceinline__ float bf2f(ushort_t h) {
    return __uint_as_float(((unsigned int)h) << 16);
}
__device__ __forceinline__ float gelu_tanh(float v) {
    float u = 0.7978845608028654f * fmaf(0.044715f * v, v * v, v);
    float e = __expf(2.f * u);
    float th = 1.f - 2.f / (e + 1.f);
    return 0.5f * v * (1.f + th);
}
__device__ __forceinline__ float gate_fn(float v) {
    float sg = 1.f / (1.f + __expf(-v));
    float e2 = __expf(2.f * v);
    float th = 1.f - 2.f / (e2 + 1.f);
    return th * sg;
}
__device__ __forceinline__ uint4v rev8v(uint4v a) {
    union { uint4v v; ushort_t s8[8]; } x, y;
    x.v = a;
    #pragma unroll
    for (int j = 0; j < 8; ++j) y.s8[j] = x.s8[7 - j];
    return y.v;
}

// ---------------- prep: tb GEMM + weight fragment repack ----------------
__global__ __launch_bounds__(256) void prep_kernel(
    const float* __restrict__ t, const float* __restrict__ Wt, const float* __restrict__ bt,
    const float* __restrict__ Wout, const float* __restrict__ Wf,
    const float* __restrict__ bout, const float* __restrict__ bfb,
    const float* __restrict__ W1, const float* __restrict__ b1,
    const float* __restrict__ W2, const float* __restrict__ b2,
    float* __restrict__ tb, float* __restrict__ bc, float* __restrict__ b12,
    ushort_t* __restrict__ wcf, ushort_t* __restrict__ w12f)
{
    int bx = blockIdx.x, tid = threadIdx.x;
    __shared__ float trow[256];
    if (bx < 32) {
        trow[tid] = t[bx * 256 + tid];
        __syncthreads();
        float acc = bt[tid];
        #pragma unroll 4
        for (int hh = 0; hh < 256; ++hh) acc = fmaf(trow[hh], Wt[tid * 256 + hh], acc);
        tb[bx * 256 + tid] = acc;
    } else if (bx < 64) {
        int gt = (bx - 32) * 256 + tid;       // 0..8191
        if (gt < 256) bc[gt] = bout[gt] + bfb[gt];
        if (gt < 512) b12[gt] = (gt < 256) ? b1[gt] : b2[gt - 256];
        // Wc_frag: 16 mtiles x 9 kchunks x 64 lanes x 8  (K=288: [Wout | Wf])
        for (int fg = gt; fg < 9216; fg += 8192) {
            int mt = fg / 576, rem = fg % 576;
            int kc = rem >> 6, lane = rem & 63;
            int m = mt * 16 + (lane & 15);
            int kb = kc * 32 + (lane >> 4) * 8;
            #pragma unroll
            for (int j = 0; j < 8; ++j) {
                int k = kb + j;
                float v = (k < 256) ? Wout[m * 256 + k] : Wf[m * 32 + (k - 256)];
                wcf[(size_t)fg * 8 + j] = f2bf(v);
            }
        }
    } else {
        int gt = (bx - 64) * 256 + tid;       // 0..8191
        // W12_frag: 32 mtiles x 8 kchunks x 64 lanes x 8  (M=512: [W1 ; W2])
        for (int fg = gt; fg < 16384; fg += 8192) {
            int mt = fg >> 9, rem = fg & 511;
            int kc = rem >> 6, lane = rem & 63;
            int m = mt * 16 + (lane & 15);
            int kb = kc * 32 + (lane >> 4) * 8;
            #pragma unroll
            for (int j = 0; j < 8; ++j) {
                int k = kb + j;
                float v = (m < 256) ? W1[m * 256 + k] : W2[(m - 256) * 256 + k];
                w12f[(size_t)fg * 8 + j] = f2bf(v);
            }
        }
    }
}

// ---------------- MERGED prep2 + ln (measured neutral vs split; saves a launch) ----------------
// blocks [0,512): prep2 ; blocks [512,1536): ln
__global__ __launch_bounds__(256) void prep2ln_kernel(
    const float* __restrict__ log_dt, const float* __restrict__ logA, const float* __restrict__ Aimg,
    const float* __restrict__ C_re, const float* __restrict__ C_im,
    float* __restrict__ drg, float* __restrict__ dig,
    ushort_t* __restrict__ Mfrag, ushort_t* __restrict__ Vfrag,
    const float* __restrict__ x, const float* __restrict__ tb,
    const float* __restrict__ ln_g, const float* __restrict__ ln_b,
    ushort_t* __restrict__ zbf)
{
    __shared__ __align__(16) char smem[68608];
    int bxg = blockIdx.x, tid = threadIdx.x;
    if (bxg < 512) {
        // ================= prep2 body =================
        float* drL = (float*)smem;             // 64
        float* diL = drL + 64;                 // 64
        float* crL = drL + 128;                // 64
        float* ciL = drL + 192;                // 64
        float* ktab = drL + 256;               // 128
        ushort_t* bndL = (ushort_t*)(smem + 1536);  // 128*128 ushort = 32768 B
        int bx = bxg;
        int h = bx >> 1, dir = bx & 1;
        if (tid < 64) {
            int n = tid;
            int idx = h * 64 + n;
            float dt = __expf(log_dt[h]);
            float Ar = -__expf(logA[idx]);
            float Ai = Aimg[idx];
            float dr = dt * Ar, di = dt * Ai;
            float er = __expf(dr);
            float wr_ = er * __cosf(di), wi_ = er * __sinf(di);
            float nr = wr_ - 1.f, ni = wi_;
            float inv = 1.f / (Ar * Ar + Ai * Ai);
            float qr = (nr * Ar + ni * Ai) * inv;
            float qi = (ni * Ar - nr * Ai) * inv;
            float cr = C_re[dir * 16384 + idx], ci = C_im[dir * 16384 + idx];
            drL[n] = dr; diL[n] = di;
            crL[n] = 2.f * (cr * qr - ci * qi);
            ciL[n] = 2.f * (cr * qi + ci * qr);
            if (dir == 0) { drg[idx] = dr; dig[idx] = di; }
        }
        __syncthreads();
        if (tid < 128) {
            int i = tid;
            float e = (float)(i + 1 - dir);
            #pragma unroll 4
            for (int n = 0; n < 64; ++n) {
                float ex = __expf(e * drL[n]);
                float ph = e * diL[n];
                float pr = ex * __cosf(ph), pi = ex * __sinf(ph);
                bndL[i * 128 + n]      = f2bf(crL[n] * pr - ciL[n] * pi);
                bndL[i * 128 + 64 + n] = f2bf(-(crL[n] * pi + ciL[n] * pr));
            }
        } else {
            int d = tid - 128;
            float e = (float)d;
            float acc = 0.f;
            #pragma unroll 4
            for (int n = 0; n < 64; ++n) {
                float ex = __expf(e * drL[n]);
                float ph = e * diL[n];
                acc += crL[n] * (ex * __cosf(ph)) - ciL[n] * (ex * __sinf(ph));
            }
            ktab[d] = acc;
        }
        __syncthreads();
        size_t base = (size_t)bx << 15;
        for (int idx = tid; idx < 32768; idx += 256) {
            int j = idx & 7, lane = (idx >> 3) & 63, kc = (idx >> 9) & 7, mt = idx >> 12;
            int m = mt * 16 + (lane & 15);
            int k = kc * 32 + (lane >> 4) * 8 + j;
            float v;
            if (k < 128) {
                int d = m - k - dir;
                v = (d >= 0) ? ktab[d] : 0.f;
            } else {
                v = bf2f(bndL[m * 128 + (k - 128)]);
            }
            Mfrag[base + idx] = f2bf(v);
        }
        if (dir == 0) {
            size_t vbase = (size_t)h << 14;
            for (int idx = tid; idx < 16384; idx += 256) {
                int j = idx & 7, lane = (idx >> 3) & 63, kc = (idx >> 9) & 3, mt = idx >> 11;
                int s = mt * 16 + (lane & 15);
                int k = kc * 32 + (lane >> 4) * 8 + j;
                int n = s & 63;
                float e = (float)(127 - k);
                float ex = __expf(e * drL[n]);
                float ph = e * diL[n];
                float v = (s < 64) ? ex * __cosf(ph) : ex * __sinf(ph);
                Vfrag[vbase + idx] = f2bf(v);
            }
        }
    } else {
        // ================= ln body (single-pass; verified R3-R11) =================
        float* Xs = (float*)smem;              // [256][65] flattened = 66560 B
        float* rs = (float*)(smem + 66560);    // [4][64]
        float* rq = rs + 256;                  // [4][64]
        int bx = bxg - 512;
        int b = bx >> 5, l0 = (bx & 31) << 6;
        const float* xb = x + (size_t)b * (Hh * (size_t)Ll) + l0;
        const float* tbp = tb + b * 256;
        int f4 = tid & 15, h0 = tid >> 4;
        #pragma unroll
        for (int i = 0; i < 16; ++i) {
            int h = i * 16 + h0;
            float4 v = *((const float4*)(xb + (size_t)h * Ll) + f4);
            float tv = tbp[h];
            Xs[h * 65 + f4 * 4 + 0] = v.x + tv;
            Xs[h * 65 + f4 * 4 + 1] = v.y + tv;
            Xs[h * 65 + f4 * 4 + 2] = v.z + tv;
            Xs[h * 65 + f4 * 4 + 3] = v.w + tv;
        }
        __syncthreads();
        int l = tid & 63, qd = tid >> 6;
        float sum = 0.f, ssq = 0.f;
        #pragma unroll 8
        for (int i = 0; i < 64; ++i) {
            float v = Xs[(qd * 64 + i) * 65 + l];
            sum += v; ssq = fmaf(v, v, ssq);
        }
        rs[qd * 64 + l] = sum; rq[qd * 64 + l] = ssq;
        __syncthreads();
        sum = rs[l] + rs[64 + l] + rs[128 + l] + rs[192 + l];
        ssq = rq[l] + rq[64 + l] + rq[128 + l] + rq[192 + l];
        float mean = sum * (1.f / 256.f);
        float var = fmaf(ssq, 1.f / 256.f, -mean * mean);
        float rstd = rsqrtf(var + 1e-5f);
        ushort_t* zp = zbf + (size_t)b * (Hh * (size_t)Ll) + l0 + l;
        #pragma unroll 8
        for (int i = 0; i < 64; ++i) {
            int h = qd * 64 + i;
            float v = Xs[h * 65 + l];
            zp[(size_t)h * Ll] = f2bf((v - mean) * rstd * ln_g[h] + ln_b[h]);
        }
    }
}

// ---------------- mega SSM (R8 structure + scan reg-prefetch; measured best R11) ----------------
__global__ __launch_bounds__(256) void ssm_mega_kernel(
    const ushort_t* __restrict__ zbf,
    const float* __restrict__ drg, const float* __restrict__ dig, const float* __restrict__ Dv,
    const ushort_t* __restrict__ Mfrag, const ushort_t* __restrict__ Vfrag,
    ushort_t* __restrict__ ya)
{
    __shared__ ushort_t Zs[64 * 136];
    __shared__ ushort_t Ssf[64 * 136];
    __shared__ ushort_t Ssb[64 * 136];
    __shared__ float Qb[2 * 128 * 17];
    int tid = threadIdx.x, lane = tid & 63, w = tid >> 6;
    int q = lane >> 4, cl = lane & 15;
    int h = blockIdx.x, cb = blockIdx.y;
    int b0 = cb * 4;
    for (int i = tid; i < 1024; i += 256) {
        int bsub = i >> 8, t8 = (i & 255) * 8;
        const ushort_t* zrow = zbf + ((size_t)((b0 + bsub) * 256 + h) << 11);
        *(uint4v*)&Zs[(bsub * 16 + (t8 >> 7)) * 136 + (t8 & 127)] = *(const uint4v*)(zrow + t8);
    }
    float dr0 = drg[h * 64 + lane], di0 = dig[h * 64 + lane];
    float ex128 = __expf(128.f * dr0);
    float w128r = ex128 * __cosf(128.f * di0);
    float w128i = ex128 * __sinf(128.f * di0);
    float Dh = Dv[h];
    const ushort_t* vbase = Vfrag + ((size_t)h << 14);
    const ushort_t* mbase0 = Mfrag + ((size_t)(h * 2) << 15);
    const ushort_t* mbase1 = Mfrag + ((size_t)(h * 2 + 1) << 15);
    // hoist Vandermonde A-fragments (bsub-invariant): 32 VGPR
    bf16x8 vfr[4][2];
    #pragma unroll
    for (int kc = 0; kc < 4; ++kc)
        #pragma unroll
        for (int i = 0; i < 2; ++i) {
            int mt = w * 2 + i;
            vfr[kc][i] = __builtin_bit_cast(bf16x8,
                *(const uint4v*)(vbase + (((mt * 4 + kc) * 64 + lane) << 3)));
        }
    __syncthreads();
    for (int bsub = 0; bsub < 4; ++bsub) {
        f32x4 qa[2][2] = {};
        #pragma unroll
        for (int kc = 0; kc < 4; ++kc) {
            int kk = kc * 32 + q * 8;
            bf16x8 bz = __builtin_bit_cast(bf16x8,
                *(const uint4v*)&Zs[(bsub * 16 + cl) * 136 + kk]);
            bf16x8 bzr = __builtin_bit_cast(bf16x8, rev8v(
                *(const uint4v*)&Zs[(bsub * 16 + (15 - cl)) * 136 + (120 - kk)]));
            #pragma unroll
            for (int i = 0; i < 2; ++i) {
                qa[0][i] = __builtin_amdgcn_mfma_f32_16x16x32_bf16(vfr[kc][i], bz, qa[0][i], 0, 0, 0);
                qa[1][i] = __builtin_amdgcn_mfma_f32_16x16x32_bf16(vfr[kc][i], bzr, qa[1][i], 0, 0, 0);
            }
        }
        __syncthreads();
        #pragma unroll
        for (int d = 0; d < 2; ++d)
            #pragma unroll
            for (int i = 0; i < 2; ++i) {
                int mt = w * 2 + i;
                #pragma unroll
                for (int r = 0; r < 4; ++r)
                    Qb[d * 2176 + (mt * 16 + q * 4 + r) * 17 + cl] = qa[d][i][r];
            }
        __syncthreads();
        if (w < 2) {
            ushort_t* S = (w == 0) ? Ssf : Ssb;
            const float* Qp = Qb + w * 2176;
            float qr_[16], qi_[16];
            #pragma unroll
            for (int cc = 0; cc < 16; ++cc) {
                qr_[cc] = Qp[lane * 17 + cc];
                qi_[cc] = Qp[(64 + lane) * 17 + cc];
            }
            float sre = 0.f, sim = 0.f;
            #pragma unroll
            for (int cc = 0; cc < 16; ++cc) {
                S[(bsub * 16 + cc) * 136 + lane] = f2bf(sre);
                S[(bsub * 16 + cc) * 136 + 64 + lane] = f2bf(sim);
                float nre = fmaf(w128r, sre, fmaf(-w128i, sim, qr_[cc]));
                float nim = fmaf(w128r, sim, fmaf(w128i, sre, qi_[cc]));
                sre = nre; sim = nim;
            }
        }
        __syncthreads();
    }
    f32x4 accf[2][4] = {}, accb[2][4] = {};
    for (int kc = 0; kc < 8; ++kc) {
        int kk = (kc & 3) * 32 + q * 8;
        bf16x8 aff[2], afb[2];
        #pragma unroll
        for (int i = 0; i < 2; ++i) {
            int mt = w * 2 + i;
            aff[i] = __builtin_bit_cast(bf16x8, *(const uint4v*)(mbase0 + (((mt * 8 + kc) * 64 + lane) << 3)));
            afb[i] = __builtin_bit_cast(bf16x8, *(const uint4v*)(mbase1 + (((mt * 8 + kc) * 64 + lane) << 3)));
        }
        #pragma unroll
        for (int nt = 0; nt < 4; ++nt) {
            bf16x8 bff, bfb_;
            if (kc < 4) {
                bff  = __builtin_bit_cast(bf16x8, *(const uint4v*)&Zs[(nt * 16 + cl) * 136 + kk]);
                bfb_ = __builtin_bit_cast(bf16x8, rev8v(
                       *(const uint4v*)&Zs[(nt * 16 + (15 - cl)) * 136 + (120 - kk)]));
            } else {
                bff  = __builtin_bit_cast(bf16x8, *(const uint4v*)&Ssf[(nt * 16 + cl) * 136 + kk]);
                bfb_ = __builtin_bit_cast(bf16x8, *(const uint4v*)&Ssb[(nt * 16 + cl) * 136 + kk]);
            }
            #pragma unroll
            for (int i = 0; i < 2; ++i) {
                accf[i][nt] = __builtin_amdgcn_mfma_f32_16x16x32_bf16(aff[i], bff,  accf[i][nt], 0, 0, 0);
                accb[i][nt] = __builtin_amdgcn_mfma_f32_16x16x32_bf16(afb[i], bfb_, accb[i][nt], 0, 0, 0);
            }
        }
    }
    __syncthreads();
    ushort_t* Yf = Ssf;
    ushort_t* Yb = Ssb;
    #pragma unroll
    for (int i = 0; i < 2; ++i) {
        int mt = w * 2 + i;
        #pragma unroll
        for (int nt = 0; nt < 4; ++nt) {
            int col = nt * 16 + cl;
            #pragma unroll
            for (int r = 0; r < 4; ++r) {
                int m = mt * 16 + q * 4 + r;
                Yf[col * 136 + m] = f2bf(accf[i][nt][r]);
                Yb[col * 136 + m] = f2bf(accb[i][nt][r]);
            }
        }
    }
    __syncthreads();
    for (int u = tid; u < 1024; u += 256) {
        int col = u >> 4, i0 = (u & 15) * 8;
        int bsub = col >> 4, c = col & 15;
        int colb = bsub * 16 + (15 - c);
        union { uint4v v; ushort_t s8[8]; } uf, uz, ub, uo;
        uf.v = *(const uint4v*)&Yf[col * 136 + i0];
        uz.v = *(const uint4v*)&Zs[col * 136 + i0];
        ub.v = rev8v(*(const uint4v*)&Yb[colb * 136 + (120 - i0)]);
        #pragma unroll
        for (int j = 0; j < 8; ++j) {
            float v = bf2f(uf.s8[j]) + bf2f(ub.s8[j]) + Dh * bf2f(uz.s8[j]);
            uo.s8[j] = f2bf(gelu_tanh(v));
        }
        ushort_t* yrow = ya + ((size_t)((b0 + bsub) * 256 + h) << 11);
        *(uint4v*)(yrow + c * 128 + i0) = uo.v;
    }
}

// ---------------- GEMM1: g = gate(Wc @ [ya; feat] + bc + x + tb) ----------------
// BK=64: two 32-k sub-chunks per barrier pair (10 barriers vs 18) -- both gemms
// are latency/barrier-bound (1.7-3.4 TB/s, small MFMA phases between barriers).
__global__ __launch_bounds__(256, 4) void gemm1_kernel(
    const ushort_t* __restrict__ ya, const float* __restrict__ feat,
    const float* __restrict__ x, const float* __restrict__ tb,
    const float* __restrict__ bc, const ushort_t* __restrict__ wcf,
    ushort_t* __restrict__ g)
{
    __shared__ __align__(16) ushort_t XT[64 * 72];   // [l][64k + 8 pad]
    int tid = threadIdx.x;
    int w = tid >> 6, lane = tid & 63;
    int bx = blockIdx.x;
    int b = bx >> 5;
    int l0 = (bx & 31) << 6;
    f32x4 acc[4][4] = {};
    int kk = tid >> 3, ng = tid & 7;
    for (int kc = 0; kc < 5; ++kc) {                 // K=288: 4x64 + 1x32
        int nsub = (kc < 4) ? 2 : 1;
        #pragma unroll
        for (int s = 0; s < 2; ++s) {
            if (s >= nsub) break;
            int k = kc * 64 + s * 32 + kk;
            union { uint4v v; ushort_t sv[8]; } u;
            if (k < 256) {
                u.v = *(const uint4v*)(ya + ((size_t)(b * 256 + k) << 11) + l0 + ng * 8);
            } else {
                const float* src = feat + (size_t)(b * 32 + (k - 256)) * Ll + l0 + ng * 8;
                #pragma unroll
                for (int j = 0; j < 8; ++j) u.sv[j] = f2bf(src[j]);
            }
            #pragma unroll
            for (int j = 0; j < 8; ++j) XT[(ng * 8 + j) * 72 + s * 32 + kk] = u.sv[j];
        }
        __syncthreads();
        #pragma unroll
        for (int s = 0; s < 2; ++s) {
            if (s >= nsub) break;
            int kch = kc * 2 + s;                    // 32-k chunk index 0..8
            bf16x8 af[4], bfr[4];
            #pragma unroll
            for (int i = 0; i < 4; ++i) {
                const ushort_t* p = wcf + ((size_t)((w * 4 + i) * 9 + kch) * 64 + lane) * 8;
                af[i] = __builtin_bit_cast(bf16x8, *(const uint4v*)p);
            }
            #pragma unroll
            for (int nt = 0; nt < 4; ++nt) {
                const ushort_t* p = &XT[(nt * 16 + (lane & 15)) * 72 + s * 32 + (lane >> 4) * 8];
                bfr[nt] = __builtin_bit_cast(bf16x8, *(const uint4v*)p);
            }
            #pragma unroll
            for (int i = 0; i < 4; ++i)
                #pragma unroll
                for (int nt = 0; nt < 4; ++nt)
                    acc[i][nt] = __builtin_amdgcn_mfma_f32_16x16x32_bf16(af[i], bfr[nt], acc[i][nt], 0, 0, 0);
        }
        __syncthreads();
    }
    int q = lane >> 4, nl = lane & 15;
    #pragma unroll
    for (int i = 0; i < 4; ++i) {
        #pragma unroll
        for (int nt = 0; nt < 4; ++nt) {
            int n = l0 + nt * 16 + nl;
            #pragma unroll
            for (int r = 0; r < 4; ++r) {
                int m = (w * 4 + i) * 16 + q * 4 + r;
                size_t oi = (size_t)(b * 256 + m) * Ll + n;
                float v = acc[i][nt][r] + bc[m] + tb[b * 256 + m] + x[oi];
                g[oi] = f2bf(gate_fn(v));
            }
        }
    }
}

// ---------------- GEMM2: o1 = W1@g + b1 + x ; o2 = W2@g + b2  (BK=64, 8 barriers) ----------------
__global__ __launch_bounds__(256, 4) void gemm2_kernel(
    const ushort_t* __restrict__ g, const float* __restrict__ x,
    const float* __restrict__ b12, const ushort_t* __restrict__ w12f,
    float* __restrict__ out)
{
    __shared__ __align__(16) ushort_t XT[64 * 72];
    int tid = threadIdx.x;
    int w = tid >> 6, lane = tid & 63;
    int bx = blockIdx.x;
    int half = blockIdx.y;
    int b = bx >> 5;
    int l0 = (bx & 31) << 6;
    f32x4 acc[4][4] = {};
    int kk = tid >> 3, ng = tid & 7;
    for (int kc = 0; kc < 4; ++kc) {                 // K=256: 4x64
        #pragma unroll
        for (int s = 0; s < 2; ++s) {
            int k = kc * 64 + s * 32 + kk;
            union { uint4v v; ushort_t sv[8]; } u;
            u.v = *(const uint4v*)(g + (size_t)(b * 256 + k) * Ll + l0 + ng * 8);
            #pragma unroll
            for (int j = 0; j < 8; ++j) XT[(ng * 8 + j) * 72 + s * 32 + kk] = u.sv[j];
        }
        __syncthreads();
        #pragma unroll
        for (int s = 0; s < 2; ++s) {
            int kch = kc * 2 + s;                    // 32-k chunk index 0..7
            bf16x8 af[4], bfr[4];
            #pragma unroll
            for (int i = 0; i < 4; ++i) {
                int mtg = half * 16 + w * 4 + i;
                const ushort_t* p = w12f + ((size_t)(mtg * 8 + kch) * 64 + lane) * 8;
                af[i] = __builtin_bit_cast(bf16x8, *(const uint4v*)p);
            }
            #pragma unroll
            for (int nt = 0; nt < 4; ++nt) {
                const ushort_t* p = &XT[(nt * 16 + (lane & 15)) * 72 + s * 32 + (lane >> 4) * 8];
                bfr[nt] = __builtin_bit_cast(bf16x8, *(const uint4v*)p);
            }
            #pragma unroll
            for (int i = 0; i < 4; ++i)
                #pragma unroll
                for (int nt = 0; nt < 4; ++nt)
                    acc[i][nt] = __builtin_amdgcn_mfma_f32_16x16x32_bf16(af[i], bfr[nt], acc[i][nt], 0, 0, 0);
        }
        __syncthreads();
    }
    int q = lane >> 4, nl = lane & 15;
    #pragma unroll
    for (int i = 0; i < 4; ++i) {
        #pragma unroll
        for (int nt = 0; nt < 4; ++nt) {
            int n = l0 + nt * 16 + nl;
            #pragma unroll
            for (int r = 0; r < 4; ++r) {
                int m = (w * 4 + i) * 16 + q * 4 + r;
                size_t oi = (size_t)(b * 256 + m) * Ll + n;
                float v = acc[i][nt][r] + b12[half * 256 + m];
                if (half == 0) out[oi] = v + x[oi];
                else out[(size_t)BHL + oi] = v;
            }
        }
    }
}

extern "C" void kernel_launch(void* const* d_in, const int* in_sizes, int n_in,
                              void* d_out, int out_size, void* d_ws, size_t ws_size,
                              hipStream_t stream) {
    const float* x      = (const float*)d_in[0];
    const float* t      = (const float*)d_in[1];
    const float* feat   = (const float*)d_in[2];
    const float* Wt     = (const float*)d_in[3];
    const float* bt     = (const float*)d_in[4];
    const float* ln_g   = (const float*)d_in[5];
    const float* ln_b   = (const float*)d_in[6];
    const float* log_dt = (const float*)d_in[7];
    const float* logA   = (const float*)d_in[8];
    const float* Aimg   = (const float*)d_in[9];
    const float* C_re   = (const float*)d_in[10];
    const float* C_im   = (const float*)d_in[11];
    const float* Dv     = (const float*)d_in[12];
    const float* Wout   = (const float*)d_in[13];
    const float* bout   = (const float*)d_in[14];
    const float* W1     = (const float*)d_in[15];
    const float* b1     = (const float*)d_in[16];
    const float* W2     = (const float*)d_in[17];
    const float* b2     = (const float*)d_in[18];
    const float* Wf     = (const float*)d_in[19];
    const float* bfb    = (const float*)d_in[20];

    // d_out (128 MiB): zbf [0,32Mi) | ya [32,64Mi) ; later fully overwritten by out
    char* ob = (char*)d_out;
    ushort_t* zbf = (ushort_t*)ob;
    ushort_t* yab = (ushort_t*)(ob + 33554432);
    float*    out = (float*)d_out;

    // ws: Mfrag 32 MiB (aliased by g after mega) | Vfrag 8 MiB | small tables
    char* ws = (char*)d_ws;
    ushort_t* Mfrag = (ushort_t*)ws;
    ushort_t* gbuf  = (ushort_t*)ws;                  // alias: g overwrites Mfrag (dead by gemm1)
    ushort_t* Vfrag = (ushort_t*)(ws + 33554432);
    char* ws2 = ws + 33554432 + 8388608;
    float* tb   = (float*)ws2;
    float* drg  = (float*)(ws2 + 32768);
    float* dig  = (float*)(ws2 + 98304);
    float* bc   = (float*)(ws2 + 163840);
    float* b12  = (float*)(ws2 + 164864);
    ushort_t* wcf  = (ushort_t*)(ws2 + 166912);
    ushort_t* w12f = (ushort_t*)(ws2 + 314368);

    prep_kernel<<<96, 256, 0, stream>>>(t, Wt, bt, Wout, Wf, bout, bfb, W1, b1, W2, b2,
                                        tb, bc, b12, wcf, w12f);
    prep2ln_kernel<<<1536, 256, 0, stream>>>(log_dt, logA, Aimg, C_re, C_im, drg, dig,
                                             Mfrag, Vfrag, x, tb, ln_g, ln_b, zbf);
    ssm_mega_kernel<<<dim3(256, 8), 256, 0, stream>>>(zbf, drg, dig, Dv, Mfrag, Vfrag, yab);
    gemm1_kernel<<<1024, 256, 0, stream>>>(yab, feat, x, tb, bc, wcf, gbuf);
    gemm2_kernel<<<dim3(1024, 2), 256, 0, stream>>>(gbuf, x, b12, w12f, out);
}